// Round 8
// baseline (267.225 us; speedup 1.0000x reference)
//
#include <hip/hip_runtime.h>

// CosineLoss: out = mean_i( 1 - dot(a_i,b_i) / (||a_i||*||b_i||) )
// inputs: d_in[0]=cxr (N,D) f32, d_in[1]=ehr (N,D) f32; N=16384, D=2048.
//
// R11. Ladder so far: 96.6 (R0) -> 79.5 (R9: nt on A) -> ~70us (R10: nt on
// both; partial fell out of rocprof top-5). Both wins were latency-path
// cuts (nt skips cache allocation). Delivered ~3.8 TB/s vs 6.9 TB/s the
// harness fill kernel proves the fabric can do.
//
// The occupancy axis was only ever tested CONFOUNDED (R6 spilled: VGPR
// capped 32, 33MB scratch). R11 retests it clean: one change vs R10 --
// 32 waves/CU (launch_bounds(256,8), GRID 2048, 2 rows/wave), row split
// into two 4+4 float4 chunks so load-dest arrays = 32 VGPR, no spill
// under the 64-VGPR cap. Both arrays stay nt.
// Checks: VGPR<=64, WRITE_SIZE ~KB (no spill), Occupancy ~65%.

#define ROWS 16384
#define COLS_V4 512                 // float4 per row (D=2048)
#define BLOCK 256                   // 4 waves per block
#define WPB (BLOCK / 64)            // 4
#define GRID 2048                   // 8 blocks/CU -> 32 waves/CU
#define RPW (ROWS / (GRID * WPB))   // 2 consecutive rows per wave

typedef float v4f __attribute__((ext_vector_type(4)));

__global__ __launch_bounds__(BLOCK, 8) void cosine_partial_kernel(
    const float* __restrict__ A,
    const float* __restrict__ B,
    float* __restrict__ partial) {
    const int t    = threadIdx.x;
    const int wave = t >> 6;
    const int lane = t & 63;
    const int row0 = (blockIdx.x * WPB + wave) * RPW;

    const v4f* __restrict__ A4 = (const v4f*)A;
    const v4f* __restrict__ B4 = (const v4f*)B;

    float wloss = 0.0f;   // meaningful in lane 0 only

    for (int r = 0; r < RPW; ++r) {
        const size_t base = (size_t)(row0 + r) * COLS_V4 + lane;
        const v4f* __restrict__ a = A4 + base;
        const v4f* __restrict__ b = B4 + base;

        float d = 0.0f, na = 0.0f, nb = 0.0f;
        #pragma unroll
        for (int h = 0; h < 2; ++h) {
            v4f va[4], vb[4];
            #pragma unroll
            for (int c = 0; c < 4; ++c) {
                const size_t off = (size_t)(h * 4 + c) * 64;
                va[c] = __builtin_nontemporal_load(a + off);  // nt
                vb[c] = __builtin_nontemporal_load(b + off);  // nt
            }
            #pragma unroll
            for (int c = 0; c < 4; ++c) {
                d  += va[c].x * vb[c].x + va[c].y * vb[c].y
                    + va[c].z * vb[c].z + va[c].w * vb[c].w;
                na += va[c].x * va[c].x + va[c].y * va[c].y
                    + va[c].z * va[c].z + va[c].w * va[c].w;
                nb += vb[c].x * vb[c].x + vb[c].y * vb[c].y
                    + vb[c].z * vb[c].z + vb[c].w * vb[c].w;
            }
        }

        // wave reduce, once per 16KB row
        #pragma unroll
        for (int off = 32; off > 0; off >>= 1) {
            d  += __shfl_down(d,  off, 64);
            na += __shfl_down(na, off, 64);
            nb += __shfl_down(nb, off, 64);
        }
        if (lane == 0) wloss += 1.0f - d * rsqrtf(na * nb);
    }

    __shared__ float s_loss[WPB];
    if (lane == 0) s_loss[wave] = wloss;
    __syncthreads();
    if (t == 0) {
        float s = 0.0f;
        #pragma unroll
        for (int w = 0; w < WPB; ++w) s += s_loss[w];
        partial[blockIdx.x] = s;
    }
}

__global__ __launch_bounds__(256) void cosine_reduce_kernel(
    const float* __restrict__ partial,
    float* __restrict__ out) {
    const int t = threadIdx.x;
    float s = 0.0f;
    #pragma unroll
    for (int i = 0; i < GRID / 256; ++i) s += partial[t + i * 256];
    #pragma unroll
    for (int off = 32; off > 0; off >>= 1) s += __shfl_down(s, off, 64);

    __shared__ float s_sum[4];
    const int wave = t >> 6;
    const int lane = t & 63;
    if (lane == 0) s_sum[wave] = s;
    __syncthreads();
    if (t == 0) {
        out[0] = (s_sum[0] + s_sum[1] + s_sum[2] + s_sum[3]) * (1.0f / (float)ROWS);
    }
}

extern "C" void kernel_launch(void* const* d_in, const int* in_sizes, int n_in,
                              void* d_out, int out_size, void* d_ws, size_t ws_size,
                              hipStream_t stream) {
    const float* cxr = (const float*)d_in[0];
    const float* ehr = (const float*)d_in[1];
    float* out     = (float*)d_out;
    float* partial = (float*)d_ws;   // GRID floats = 8 KB, fully overwritten

    cosine_partial_kernel<<<GRID, BLOCK, 0, stream>>>(cxr, ehr, partial);
    cosine_reduce_kernel<<<1, 256, 0, stream>>>(partial, out);
}

// Round 11
// 256.023 us; speedup vs baseline: 1.0438x; 1.0438x over previous
//
#include <hip/hip_runtime.h>

// CosineLoss: out = mean_i( 1 - dot(a_i,b_i) / (||a_i||*||b_i||) )
// inputs: d_in[0]=cxr (N,D) f32, d_in[1]=ehr (N,D) f32; N=16384, D=2048.
//
// R14 = R12/R13 experiment, hardened resubmission (two container failures;
// R8 precedent shows compile errors report cleanly, and this kernel has no
// hang hazard: no inter-wave deps in main loop, vmcnt waits can't deadlock,
// all addresses in bounds -> infra flake suspected; macro -> function as
// cheap de-risking).
//
// Model: per-CU outstanding-bytes cap (~4-6KB by Little's law from R5) on
// REGISTER-destined loads. nt cut latency (96.6 -> ~70us); depth/waves/
// pattern all null because the cap binds. Fill kernel (6.9 TB/s) proves
// fabric headroom over our 3.8.
//
// Test: global_load_lds returns to LDS, bypassing the VGPR return queue.
// 3-deep row pipeline, counted vmcnt(4) (never 0 mid-loop), NO barrier in
// main loop (each wave computes exactly the slice it staged), aux=2 (SLC/
// streaming) keeps the nt latency win. ~96KB/CU issued-outstanding.
// Win => cap was register-path. Flat => structural cap, ROOFLINE.

#define ROWS 16384
#define COLS 2048
#define BLOCK 512                  // 8 waves
#define GRID 512                   // 2 blocks/CU
#define STEPS (ROWS / GRID)        // 32 rows per block
#define WPB (BLOCK / 64)           // 8
#define PIPE 3

typedef float v4f __attribute__((ext_vector_type(4)));

__device__ __forceinline__ void stage_row(
    const float* __restrict__ g, v4f* lds_slice_base) {
    // one global_load_lds_dwordx4 per wave: lane i -> base + i*16
    __builtin_amdgcn_global_load_lds(
        (const __attribute__((address_space(1))) void*)g,
        (__attribute__((address_space(3))) void*)lds_slice_base,
        16, 0, 2);
}

__global__ __launch_bounds__(BLOCK, 4) void cosine_partial_kernel(
    const float* __restrict__ A,
    const float* __restrict__ B,
    float* __restrict__ partial) {
    const int t    = threadIdx.x;
    const int wave = t >> 6;
    const int lane = t & 63;
    const int row0 = blockIdx.x * STEPS;

    __shared__ v4f bufA[PIPE][BLOCK];          // 24 KB
    __shared__ v4f bufB[PIPE][BLOCK];          // 24 KB
    __shared__ float s_part[STEPS][WPB][3];    // 3 KB

    // prologue: 3 steps in flight (6 VMEM ops/wave outstanding)
    #pragma unroll
    for (int s = 0; s < PIPE; ++s) {
        const size_t gbase = (size_t)(row0 + s) * COLS + (size_t)t * 4;
        stage_row(A + gbase, &bufA[s][wave * 64]);
        stage_row(B + gbase, &bufB[s][wave * 64]);
    }

    int p = 0;
    for (int s = 0; s < STEPS; ++s) {
        // counted drain: step s's 2 loads are the oldest; steps s+1,s+2
        // (4 ops) stay in flight. Tail steps drain 2 -> 0.
        if (s <= STEPS - 3) {
            asm volatile("s_waitcnt vmcnt(4)" ::: "memory");
        } else if (s == STEPS - 2) {
            asm volatile("s_waitcnt vmcnt(2)" ::: "memory");
        } else {
            asm volatile("s_waitcnt vmcnt(0)" ::: "memory");
        }
        __builtin_amdgcn_sched_barrier(0);

        // each wave reads exactly the 1KB slices IT staged -> no barrier
        v4f va = bufA[p][t];
        v4f vb = bufB[p][t];
        float d  = va.x * vb.x + va.y * vb.y + va.z * vb.z + va.w * vb.w;
        float na = va.x * va.x + va.y * va.y + va.z * va.z + va.w * va.w;
        float nb = vb.x * vb.x + vb.y * vb.y + vb.z * vb.z + vb.w * vb.w;

        #pragma unroll
        for (int off = 32; off > 0; off >>= 1) {
            d  += __shfl_down(d,  off, 64);
            na += __shfl_down(na, off, 64);
            nb += __shfl_down(nb, off, 64);
        }
        if (lane == 0) {
            s_part[s][wave][0] = d;
            s_part[s][wave][1] = na;
            s_part[s][wave][2] = nb;
        }

        // pin: next stage must not hoist above the ds_reads/shuffles
        __builtin_amdgcn_sched_barrier(0);
        if (s + PIPE < STEPS) {
            const size_t gbase = (size_t)(row0 + s + PIPE) * COLS + (size_t)t * 4;
            stage_row(A + gbase, &bufA[p][wave * 64]);
            stage_row(B + gbase, &bufB[p][wave * 64]);
        }
        if (++p == PIPE) p = 0;
    }

    __syncthreads();

    // threads 0..31 (wave 0) each finish one row
    float loss = 0.f;
    if (t < STEPS) {
        float d = 0.f, na = 0.f, nb = 0.f;
        #pragma unroll
        for (int w = 0; w < WPB; ++w) {
            d  += s_part[t][w][0];
            na += s_part[t][w][1];
            nb += s_part[t][w][2];
        }
        loss = 1.0f - d * rsqrtf(na * nb);
    }
    if (wave == 0) {
        #pragma unroll
        for (int off = 16; off > 0; off >>= 1)
            loss += __shfl_down(loss, off, 64);   // lanes >=32 contribute 0
        if (lane == 0) partial[blockIdx.x] = loss;
    }
}

__global__ __launch_bounds__(256) void cosine_reduce_kernel(
    const float* __restrict__ partial,
    float* __restrict__ out) {
    const int t = threadIdx.x;
    float s = partial[t] + partial[t + 256];   // GRID = 512
    #pragma unroll
    for (int off = 32; off > 0; off >>= 1) s += __shfl_down(s, off, 64);

    __shared__ float s_sum[4];
    const int wave = t >> 6;
    const int lane = t & 63;
    if (lane == 0) s_sum[wave] = s;
    __syncthreads();
    if (t == 0) {
        out[0] = (s_sum[0] + s_sum[1] + s_sum[2] + s_sum[3]) * (1.0f / (float)ROWS);
    }
}

extern "C" void kernel_launch(void* const* d_in, const int* in_sizes, int n_in,
                              void* d_out, int out_size, void* d_ws, size_t ws_size,
                              hipStream_t stream) {
    const float* cxr = (const float*)d_in[0];
    const float* ehr = (const float*)d_in[1];
    float* out     = (float*)d_out;
    float* partial = (float*)d_ws;   // GRID floats = 2 KB, fully overwritten

    cosine_partial_kernel<<<GRID, BLOCK, 0, stream>>>(cxr, ehr, partial);
    cosine_reduce_kernel<<<1, 256, 0, stream>>>(partial, out);
}